// Round 1
// baseline (208.386 us; speedup 1.0000x reference)
//
#include <hip/hip_runtime.h>
#include <cstdint>
#include <cstddef>

typedef __bf16 bf16x8 __attribute__((ext_vector_type(8)));
typedef float f32x4 __attribute__((ext_vector_type(4)));
typedef unsigned int u32x4 __attribute__((ext_vector_type(4)));

union U16x8 {
  u32x4 u;
  bf16x8 b;
  unsigned short s[8];
};

__device__ __forceinline__ unsigned short f2bf(float f) {
  union { float f; unsigned u; } v;
  v.f = f;
  unsigned r = v.u + 0x7FFFu + ((v.u >> 16) & 1u);
  return (unsigned short)(r >> 16);
}

// ---------------- weight prep: f32 -> bf16, transposed to [N][K] ----------------
__global__ __launch_bounds__(256) void prep_weights(
    const float* __restrict__ Wqkv, const float* __restrict__ Wout,
    const float* __restrict__ Wf1, const float* __restrict__ Wf2,
    unsigned short* __restrict__ qkv_t, unsigned short* __restrict__ out_t,
    unsigned short* __restrict__ f1_t, unsigned short* __restrict__ f2_t) {
  int i = blockIdx.x * 256 + threadIdx.x;
  if (i < 768 * 256) { int n = i >> 8, k = i & 255; qkv_t[i] = f2bf(Wqkv[k * 768 + n]); return; }
  i -= 768 * 256;
  if (i < 256 * 256) { int n = i >> 8, k = i & 255; out_t[i] = f2bf(Wout[k * 256 + n]); return; }
  i -= 256 * 256;
  if (i < 512 * 256) { int n = i >> 8, k = i & 255; f1_t[i] = f2bf(Wf1[k * 512 + n]); return; }
  i -= 512 * 256;
  if (i < 256 * 512) { int n = i >> 9, k = i & 511; f2_t[i] = f2bf(Wf2[k * 256 + n]); return; }
}

// ---------------- LayerNorm (f32 in -> bf16 out), 1 wave per 256-wide row ----------------
__global__ __launch_bounds__(256) void ln_kernel(
    const float* __restrict__ x, const float* __restrict__ gw, const float* __restrict__ bw,
    unsigned short* __restrict__ out) {
  const int row = blockIdx.x * 4 + (threadIdx.x >> 6);
  const int lane = threadIdx.x & 63;
  const float4 v = *reinterpret_cast<const float4*>(x + (size_t)row * 256 + lane * 4);
  float s = v.x + v.y + v.z + v.w;
  float s2 = v.x * v.x + v.y * v.y + v.z * v.z + v.w * v.w;
#pragma unroll
  for (int m = 1; m < 64; m <<= 1) {
    s += __shfl_xor(s, m);
    s2 += __shfl_xor(s2, m);
  }
  const float mean = s * (1.f / 256.f);
  const float var = s2 * (1.f / 256.f) - mean * mean;
  const float rstd = rsqrtf(var + 1e-5f);
  const float4 gg = *reinterpret_cast<const float4*>(gw + lane * 4);
  const float4 bb = *reinterpret_cast<const float4*>(bw + lane * 4);
  ushort4 o;
  o.x = f2bf((v.x - mean) * rstd * gg.x + bb.x);
  o.y = f2bf((v.y - mean) * rstd * gg.y + bb.y);
  o.z = f2bf((v.z - mean) * rstd * gg.z + bb.z);
  o.w = f2bf((v.w - mean) * rstd * gg.w + bb.w);
  *reinterpret_cast<ushort4*>(out + (size_t)row * 256 + lane * 4) = o;
}

// ---------------- direct-global MFMA GEMM: C[M][N] = A[M][K](bf16) @ Wt[N][K](bf16)^T ----------------
// EPI 0: out bf16 = acc + bias
// EPI 1: out f32  = acc + bias + res[m*256+n]   (requires N==256)
// EPI 2: out bf16 = gelu_exact(acc + bias)
template <int EPI, int K, int N>
__global__ __launch_bounds__(256) void gemm_kernel(
    const unsigned short* __restrict__ A, const unsigned short* __restrict__ Wt,
    const float* __restrict__ bias, const float* __restrict__ res, void* __restrict__ outp) {
  const int w = threadIdx.x >> 6;
  const int lane = threadIdx.x & 63;
  const int l15 = lane & 15;
  const int g = lane >> 4;
  const int m0 = blockIdx.x * 128 + w * 32;
  const int n0 = blockIdx.y * 64;

  f32x4 acc[2][4];
#pragma unroll
  for (int mf = 0; mf < 2; ++mf)
#pragma unroll
    for (int nf = 0; nf < 4; ++nf) acc[mf][nf] = f32x4{0.f, 0.f, 0.f, 0.f};

#pragma unroll 4
  for (int kk = 0; kk < K / 32; ++kk) {
    U16x8 a[2], bfr[4];
#pragma unroll
    for (int mf = 0; mf < 2; ++mf)
      a[mf].u = *reinterpret_cast<const u32x4*>(A + (size_t)(m0 + mf * 16 + l15) * K + kk * 32 + g * 8);
#pragma unroll
    for (int nf = 0; nf < 4; ++nf)
      bfr[nf].u = *reinterpret_cast<const u32x4*>(Wt + (size_t)(n0 + nf * 16 + l15) * K + kk * 32 + g * 8);
#pragma unroll
    for (int mf = 0; mf < 2; ++mf)
#pragma unroll
      for (int nf = 0; nf < 4; ++nf)
        acc[mf][nf] = __builtin_amdgcn_mfma_f32_16x16x32_bf16(a[mf].b, bfr[nf].b, acc[mf][nf], 0, 0, 0);
  }

#pragma unroll
  for (int mf = 0; mf < 2; ++mf)
#pragma unroll
    for (int nf = 0; nf < 4; ++nf)
#pragma unroll
      for (int r = 0; r < 4; ++r) {
        const int m = m0 + mf * 16 + g * 4 + r;
        const int n = n0 + nf * 16 + l15;
        float v = acc[mf][nf][r] + bias[n];
        if constexpr (EPI == 1) {
          v += res[(size_t)m * 256 + n];
          reinterpret_cast<float*>(outp)[(size_t)m * 256 + n] = v;
        } else if constexpr (EPI == 2) {
          v = 0.5f * v * (1.0f + erff(v * 0.70710678118654752f));
          reinterpret_cast<unsigned short*>(outp)[(size_t)m * N + n] = f2bf(v);
        } else {
          reinterpret_cast<unsigned short*>(outp)[(size_t)m * N + n] = f2bf(v);
        }
      }
}

// ---------------- V transpose: qkv[:,512:768] (per b,h: [c][dk]) -> vt [b][h][dk][c] ----------------
__global__ __launch_bounds__(256) void transpose_v(
    const unsigned short* __restrict__ qkv, unsigned short* __restrict__ vt) {
  __shared__ unsigned short tile[64][40];
  const int t = threadIdx.x;
  const int ct = blockIdx.x & 31;
  const int h = (blockIdx.x >> 5) & 7;
  const int b = blockIdx.x >> 8;
  {
    const int c = t >> 2;
    const int dkb = (t & 3) * 8;
    U16x8 v;
    v.u = *reinterpret_cast<const u32x4*>(qkv + (size_t)(b * 2048 + ct * 64 + c) * 768 + 512 + h * 32 + dkb);
#pragma unroll
    for (int j = 0; j < 8; ++j) tile[c][dkb + j] = v.s[j];
  }
  __syncthreads();
  {
    const int dk = t >> 3;
    const int cb = (t & 7) * 8;
    U16x8 v;
#pragma unroll
    for (int j = 0; j < 8; ++j) v.s[j] = tile[cb + j][dk];
    *reinterpret_cast<u32x4*>(vt + (size_t)((b * 8 + h) * 32 + dk) * 2048 + ct * 64 + cb) = v.u;
  }
}

// ---------------- flash attention: block = (b, 32-row q-tile), wave = head ----------------
__global__ __launch_bounds__(512) void attn_kernel(
    const unsigned short* __restrict__ qkv, const unsigned short* __restrict__ vt,
    const float* __restrict__ adj, unsigned short* __restrict__ out) {
  __shared__ __align__(16) unsigned short p_lds[8][2048];  // per-wave 32x64 P tile, XOR-swizzled
  const int h = threadIdx.x >> 6;
  const int lane = threadIdx.x & 63;
  const int l15 = lane & 15;
  const int g = lane >> 4;
  const int qt = blockIdx.x;
  const int b = blockIdx.y;
  const int q0 = qt * 32;
  const float scale = 0.17677669529663689f;  // 1/sqrt(32)

  U16x8 qa[2];
#pragma unroll
  for (int mf = 0; mf < 2; ++mf)
    qa[mf].u = *reinterpret_cast<const u32x4*>(
        qkv + (size_t)(b * 2048 + q0 + mf * 16 + l15) * 768 + h * 32 + g * 8);

  f32x4 o[2][2];
  float mrun[2][4], lrun[2][4];
#pragma unroll
  for (int mf = 0; mf < 2; ++mf) {
#pragma unroll
    for (int n = 0; n < 2; ++n) o[mf][n] = f32x4{0.f, 0.f, 0.f, 0.f};
#pragma unroll
    for (int r = 0; r < 4; ++r) { mrun[mf][r] = -1e30f; lrun[mf][r] = 0.f; }
  }

  const float* bptr = adj + (size_t)b * 2048 * 2048;

  for (int kt = 0; kt < 32; ++kt) {
    const int kv0 = kt * 64;
    U16x8 kb[4];
#pragma unroll
    for (int f = 0; f < 4; ++f)
      kb[f].u = *reinterpret_cast<const u32x4*>(
          qkv + (size_t)(b * 2048 + kv0 + f * 16 + l15) * 768 + 256 + h * 32 + g * 8);

    f32x4 s[2][4];
    const f32x4 z = {0.f, 0.f, 0.f, 0.f};
#pragma unroll
    for (int mf = 0; mf < 2; ++mf)
#pragma unroll
      for (int f = 0; f < 4; ++f)
        s[mf][f] = __builtin_amdgcn_mfma_f32_16x16x32_bf16(qa[mf].b, kb[f].b, z, 0, 0, 0);

    // scale + adj_bias (C-layout: row=(g*4+r), col=l15 within each 16x16 frag)
#pragma unroll
    for (int mf = 0; mf < 2; ++mf)
#pragma unroll
      for (int f = 0; f < 4; ++f)
#pragma unroll
        for (int r = 0; r < 4; ++r)
          s[mf][f][r] = fmaf(s[mf][f][r], scale,
                             bptr[(size_t)(q0 + mf * 16 + g * 4 + r) * 2048 + kv0 + f * 16 + l15]);

    // online softmax per row (row lives across the 16 lanes of one g-group)
    float alpha[2][4];
#pragma unroll
    for (int mf = 0; mf < 2; ++mf)
#pragma unroll
      for (int r = 0; r < 4; ++r) {
        float mx = fmaxf(fmaxf(s[mf][0][r], s[mf][1][r]), fmaxf(s[mf][2][r], s[mf][3][r]));
        mx = fmaxf(mx, __shfl_xor(mx, 1));
        mx = fmaxf(mx, __shfl_xor(mx, 2));
        mx = fmaxf(mx, __shfl_xor(mx, 4));
        mx = fmaxf(mx, __shfl_xor(mx, 8));
        const float mnew = fmaxf(mrun[mf][r], mx);
        const float a = __expf(mrun[mf][r] - mnew);
        mrun[mf][r] = mnew;
        float rs = 0.f;
#pragma unroll
        for (int f = 0; f < 4; ++f) {
          const float p = __expf(s[mf][f][r] - mnew);
          s[mf][f][r] = p;
          rs += p;
        }
        rs += __shfl_xor(rs, 1);
        rs += __shfl_xor(rs, 2);
        rs += __shfl_xor(rs, 4);
        rs += __shfl_xor(rs, 8);
        lrun[mf][r] = lrun[mf][r] * a + rs;
        alpha[mf][r] = a;
      }

#pragma unroll
    for (int mf = 0; mf < 2; ++mf)
#pragma unroll
      for (int n = 0; n < 2; ++n)
#pragma unroll
        for (int r = 0; r < 4; ++r) o[mf][n][r] *= alpha[mf][r];

    // P -> LDS (bf16, XOR swizzle to kill ds_read bank conflicts)
#pragma unroll
    for (int mf = 0; mf < 2; ++mf)
#pragma unroll
      for (int f = 0; f < 4; ++f)
#pragma unroll
        for (int r = 0; r < 4; ++r) {
          const int rl = mf * 16 + g * 4 + r;
          const int col = f * 16 + l15;
          p_lds[h][rl * 64 + (col ^ ((rl & 7) << 3))] = f2bf(s[mf][f][r]);
        }

    // P A-frags from LDS, V^T B-frags from global, PV accumulate
    U16x8 pa[2][2], vb[2][2];
#pragma unroll
    for (int mf = 0; mf < 2; ++mf)
#pragma unroll
      for (int c = 0; c < 2; ++c) {
        const int rl = mf * 16 + l15;
        const int cb = c * 32 + g * 8;
        pa[mf][c].u = *reinterpret_cast<const u32x4*>(&p_lds[h][rl * 64 + (cb ^ ((rl & 7) << 3))]);
      }
#pragma unroll
    for (int c = 0; c < 2; ++c)
#pragma unroll
      for (int n = 0; n < 2; ++n)
        vb[c][n].u = *reinterpret_cast<const u32x4*>(
            vt + (size_t)((b * 8 + h) * 32 + n * 16 + l15) * 2048 + kv0 + c * 32 + g * 8);

#pragma unroll
    for (int mf = 0; mf < 2; ++mf)
#pragma unroll
      for (int n = 0; n < 2; ++n)
#pragma unroll
        for (int c = 0; c < 2; ++c)
          o[mf][n] = __builtin_amdgcn_mfma_f32_16x16x32_bf16(pa[mf][c].b, vb[c][n].b, o[mf][n], 0, 0, 0);
  }

#pragma unroll
  for (int mf = 0; mf < 2; ++mf)
#pragma unroll
    for (int r = 0; r < 4; ++r) {
      const float inv = 1.0f / lrun[mf][r];
#pragma unroll
      for (int n = 0; n < 2; ++n)
        out[(size_t)(b * 2048 + q0 + mf * 16 + g * 4 + r) * 256 + h * 32 + n * 16 + l15] =
            f2bf(o[mf][n][r] * inv);
    }
}

extern "C" void kernel_launch(void* const* d_in, const int* in_sizes, int n_in,
                              void* d_out, int out_size, void* d_ws, size_t ws_size,
                              hipStream_t stream) {
  const float* h_in  = (const float*)d_in[0];
  const float* adj   = (const float*)d_in[1];
  const float* Wqkv  = (const float*)d_in[2];
  const float* bqkv  = (const float*)d_in[3];
  const float* Wout  = (const float*)d_in[4];
  const float* bout  = (const float*)d_in[5];
  const float* g1    = (const float*)d_in[6];
  const float* beta1 = (const float*)d_in[7];
  const float* g2    = (const float*)d_in[8];
  const float* beta2 = (const float*)d_in[9];
  const float* Wf1   = (const float*)d_in[10];
  const float* bf1   = (const float*)d_in[11];
  const float* Wf2   = (const float*)d_in[12];
  const float* bf2   = (const float*)d_in[13];

  char* ws = (char*)d_ws;
  unsigned short* wqkv_t = (unsigned short*)(ws);
  unsigned short* wout_t = (unsigned short*)(ws + 393216);
  unsigned short* wf1_t  = (unsigned short*)(ws + 524288);
  unsigned short* wf2_t  = (unsigned short*)(ws + 786432);
  size_t off = 1048576;
  unsigned short* h_n    = (unsigned short*)(ws + off); off += (size_t)8192 * 256 * 2;
  unsigned short* qkv    = (unsigned short*)(ws + off); off += (size_t)8192 * 768 * 2;
  unsigned short* vtb    = (unsigned short*)(ws + off); off += (size_t)1024 * 2048 * 2;
  unsigned short* attn_o = (unsigned short*)(ws + off); off += (size_t)8192 * 256 * 2;
  float*          h_mid  = (float*)(ws + off);          off += (size_t)8192 * 256 * 4;
  unsigned short* h2     = (unsigned short*)(ws + off); off += (size_t)8192 * 256 * 2;
  unsigned short* a1     = (unsigned short*)(ws + off); off += (size_t)8192 * 512 * 2;

  prep_weights<<<2048, 256, 0, stream>>>(Wqkv, Wout, Wf1, Wf2, wqkv_t, wout_t, wf1_t, wf2_t);
  ln_kernel<<<2048, 256, 0, stream>>>(h_in, g1, beta1, h_n);
  gemm_kernel<0, 256, 768><<<dim3(64, 12), 256, 0, stream>>>(h_n, wqkv_t, bqkv, nullptr, qkv);
  transpose_v<<<1024, 256, 0, stream>>>(qkv, vtb);
  attn_kernel<<<dim3(64, 4), 512, 0, stream>>>(qkv, vtb, adj, attn_o);
  gemm_kernel<1, 256, 256><<<dim3(64, 4), 256, 0, stream>>>(attn_o, wout_t, bout, h_in, h_mid);
  ln_kernel<<<2048, 256, 0, stream>>>(h_mid, g2, beta2, h2);
  gemm_kernel<2, 256, 512><<<dim3(64, 8), 256, 0, stream>>>(h2, wf1_t, bf1, nullptr, a1);
  gemm_kernel<1, 512, 256><<<dim3(64, 4), 256, 0, stream>>>(a1, wf2_t, bf2, h_mid, (float*)d_out);
}